// Round 2
// baseline (610.115 us; speedup 1.0000x reference)
//
#include <hip/hip_runtime.h>
#include <hip/hip_bf16.h>

typedef __attribute__((ext_vector_type(8))) short short8;
typedef __attribute__((ext_vector_type(4))) float f32x4;

#define NROWS 32768
#define CDIM 1024
#define BNC 256
#define TOPK 128

struct alignas(8) U4 { unsigned short x, y, z, w; };

__device__ __forceinline__ unsigned short f2bf(float f){
  union { float f; unsigned u; } v; v.f = f;
  unsigned r = v.u + 0x7FFFu + ((v.u >> 16) & 1u);
  return (unsigned short)(r >> 16);
}
__device__ __forceinline__ float bf2f(unsigned short h){
  union { unsigned u; float f; } v; v.u = ((unsigned)h) << 16;
  return v.f;
}
__device__ __forceinline__ void gl16(const void* g, void* l){
  __builtin_amdgcn_global_load_lds((const __attribute__((address_space(1))) void*)g,
                                   (__attribute__((address_space(3))) void*)l, 16, 0, 0);
}
// XOR swizzle within a [128 rows][64 bytes] tile: flip 16B-granule index by row&3
__device__ __forceinline__ int swz(int o){ return o ^ (((o >> 6) & 3) << 4); }

// stage one [128 rows][32 k] bf16 tile (8 KB) into LDS (linear dest, pre-swizzled src)
__device__ __forceinline__ void stage_tile(const unsigned short* g0, int gstride,
                                           char* lds, int tid){
  #pragma unroll
  for (int i = 0; i < 2; ++i){
    int o = tid * 16 + i * 4096;
    int lb = swz(o);
    gl16((const char*)g0 + (lb >> 6) * gstride + (lb & 63), lds + o);
  }
}
// load MFMA A/B fragment: lane provides row ridx, k-granule (lane>>4), swizzled read
__device__ __forceinline__ short8 frag_ld(const char* lds, int ridx, int lane){
  int o = ridx * 64 + (((lane >> 4) ^ (ridx & 3)) << 4);
  return *(const short8*)(lds + o);
}

// ---------------- param prep ----------------
__global__ void k_wt(const float* __restrict__ W, unsigned short* __restrict__ Wt){
  __shared__ float t[32][33];
  int tx = threadIdx.x, ty = threadIdx.y;
  int bx = blockIdx.x * 32, by = blockIdx.y * 32;
  for (int i = ty; i < 32; i += 8)
    t[i][tx] = W[(by + i) * CDIM + bx + tx];
  __syncthreads();
  for (int i = ty; i < 32; i += 8)
    Wt[(bx + i) * CDIM + by + tx] = f2bf(t[tx][i]);
}

__global__ void k_split(const float* __restrict__ s, unsigned short* __restrict__ h,
                        unsigned short* __restrict__ l, int n){
  int i = blockIdx.x * 256 + threadIdx.x;
  if (i < n){
    float f = s[i];
    unsigned short hh = f2bf(f);
    h[i] = hh; l[i] = f2bf(f - bf2f(hh));
  }
}

// ---------------- bottleneck: grouped conv + BN + GELU, plus x->bf16 ----------------
__global__ __launch_bounds__(256) void k_bottleneck(
    const float* __restrict__ x,
    const float* __restrict__ cwo, const float* __restrict__ cbo,
    const float* __restrict__ go,  const float* __restrict__ bto,
    const float* __restrict__ mo,  const float* __restrict__ vo,
    const float* __restrict__ cwi, const float* __restrict__ cbi,
    const float* __restrict__ gi,  const float* __restrict__ bti,
    const float* __restrict__ mi,  const float* __restrict__ vi,
    unsigned short* __restrict__ xbf,
    unsigned short* __restrict__ uho, unsigned short* __restrict__ ulo,
    unsigned short* __restrict__ uhi, unsigned short* __restrict__ uli)
{
  const int t = threadIdx.x;
  const int r0 = blockIdx.x * 8;
  float4 cwov = ((const float4*)cwo)[t];
  float4 cwiv = ((const float4*)cwi)[t];
  float sco = go[t] * rsqrtf(vo[t] + 1e-5f);
  float sho = bto[t] - mo[t] * sco;
  float cbov = cbo[t];
  float sci = gi[t] * rsqrtf(vi[t] + 1e-5f);
  float shi = bti[t] - mi[t] * sci;
  float cbiv = cbi[t];
  for (int r = 0; r < 8; ++r){
    int row = r0 + r;
    float4 xv = ((const float4*)x)[row * 256 + t];
    U4 xb; xb.x = f2bf(xv.x); xb.y = f2bf(xv.y); xb.z = f2bf(xv.z); xb.w = f2bf(xv.w);
    ((U4*)xbf)[row * 256 + t] = xb;
    float h = xv.x*cwov.x + xv.y*cwov.y + xv.z*cwov.z + xv.w*cwov.w + cbov;
    h = h * sco + sho;
    float u = 0.5f * h * (1.0f + erff(h * 0.70710678118654752f));
    unsigned short uh = f2bf(u);
    uho[row*BNC + t] = uh; ulo[row*BNC + t] = f2bf(u - bf2f(uh));
    h = xv.x*cwiv.x + xv.y*cwiv.y + xv.z*cwiv.z + xv.w*cwiv.w + cbiv;
    h = h * sci + shi;
    u = 0.5f * h * (1.0f + erff(h * 0.70710678118654752f));
    uh = f2bf(u);
    uhi[row*BNC + t] = uh; uli[row*BNC + t] = f2bf(u - bf2f(uh));
  }
}

// ---------------- expand GEMM: L = Uh@Eh + Uh@El + Ul@Eh + eb  (split-bf16) ----------------
// A (U hi/lo) staged in LDS (double-buffered, 32 KB); B (E hi/lo, 2 MB total) read
// directly from global per-fragment (L2-resident).
__global__ __launch_bounds__(256, 3) void k_expand(
    const unsigned short* __restrict__ uh, const unsigned short* __restrict__ ul,
    const unsigned short* __restrict__ eh, const unsigned short* __restrict__ el,
    const float* __restrict__ eb, float* __restrict__ Lout)
{
  __shared__ char lds[2 * 2 * 8192];
  const int tid = threadIdx.x;
  const int lane = tid & 63, w = tid >> 6;
  const int wr = (w >> 1) * 64, wc = (w & 1) * 64;
  // XCD-bijective remap: all 8 col-blocks of a row-panel stay on one XCD
  int id = blockIdx.x + (blockIdx.y << 3);
  int xcd = id & 7, slot = id >> 3;
  const int row0 = (xcd * 32 + (slot >> 3)) * 128;
  const int col0 = (slot & 7) * 128;
  f32x4 acc[4][4] = {};
  const unsigned short* bhp[4];
  const unsigned short* blp[4];
  #pragma unroll
  for (int n = 0; n < 4; ++n){
    int col = col0 + wc + n * 16 + (lane & 15);
    size_t o = (size_t)col * BNC + ((lane >> 4) << 3);
    bhp[n] = eh + o; blp[n] = el + o;
  }
  auto stage = [&](int kt, int buf){
    char* b = lds + buf * 16384;
    stage_tile(uh + row0 * BNC + kt * 32, 512, b, tid);
    stage_tile(ul + row0 * BNC + kt * 32, 512, b + 8192, tid);
  };
  stage(0, 0);
  const int NK = BNC / 32;
  for (int kt = 0; kt < NK; ++kt){
    __syncthreads();
    if (kt + 1 < NK) stage(kt + 1, (kt & 1) ^ 1);
    const char* b = lds + (kt & 1) * 16384;
    short8 ah[4], alo[4], bh[4], bl[4];
    #pragma unroll
    for (int n = 0; n < 4; ++n){
      bh[n] = *(const short8*)(bhp[n] + kt * 32);
      bl[n] = *(const short8*)(blp[n] + kt * 32);
    }
    #pragma unroll
    for (int m = 0; m < 4; ++m){
      int ra = wr + m * 16 + (lane & 15);
      ah[m]  = frag_ld(b,        ra, lane);
      alo[m] = frag_ld(b + 8192, ra, lane);
    }
    #pragma unroll
    for (int m = 0; m < 4; ++m)
      #pragma unroll
      for (int n = 0; n < 4; ++n){
        acc[m][n] = __builtin_amdgcn_mfma_f32_16x16x32_bf16(ah[m],  bh[n], acc[m][n], 0, 0, 0);
        acc[m][n] = __builtin_amdgcn_mfma_f32_16x16x32_bf16(ah[m],  bl[n], acc[m][n], 0, 0, 0);
        acc[m][n] = __builtin_amdgcn_mfma_f32_16x16x32_bf16(alo[m], bh[n], acc[m][n], 0, 0, 0);
      }
  }
  #pragma unroll
  for (int n = 0; n < 4; ++n){
    int col = col0 + wc + n * 16 + (lane & 15);
    float ebv = eb[col];
    #pragma unroll
    for (int m = 0; m < 4; ++m){
      int row = row0 + wr + m * 16 + ((lane >> 4) << 2);
      #pragma unroll
      for (int r = 0; r < 4; ++r)
        Lout[(row + r) * CDIM + col] = acc[m][n][r] + ebv;
    }
  }
}

// ---------------- softmax + top-128 threshold + sparse score ----------------
template<bool WRITE_XS>
__global__ __launch_bounds__(256) void k_select(
    const float* __restrict__ Lg, const unsigned short* __restrict__ xg,
    unsigned short* __restrict__ obf)
{
  const int lane = threadIdx.x & 63;
  const int row = blockIdx.x * 4 + (threadIdx.x >> 6);
  const float* Lr = Lg + row * CDIM;
  float v[16];
  #pragma unroll
  for (int c = 0; c < 4; ++c){
    float4 t4 = ((const float4*)Lr)[c * 64 + lane];
    v[c*4+0] = t4.x; v[c*4+1] = t4.y; v[c*4+2] = t4.z; v[c*4+3] = t4.w;
  }
  float M = v[0];
  #pragma unroll
  for (int j = 1; j < 16; ++j) M = fmaxf(M, v[j]);
  #pragma unroll
  for (int off = 32; off > 0; off >>= 1) M = fmaxf(M, __shfl_xor(M, off));
  float S = 0.f;
  #pragma unroll
  for (int j = 0; j < 16; ++j) S += expf(v[j] - M);
  #pragma unroll
  for (int off = 32; off > 0; off >>= 1) S += __shfl_xor(S, off);
  unsigned kx[16];
  #pragma unroll
  for (int j = 0; j < 16; ++j){
    union { float f; unsigned u; } q; q.f = v[j];
    kx[j] = q.u ^ ((q.u & 0x80000000u) ? 0xFFFFFFFFu : 0x80000000u);
  }
  unsigned pref = 0;
  for (int bit = 31; bit >= 0; --bit){
    unsigned cand = pref | (1u << bit);
    int c = 0;
    #pragma unroll
    for (int j = 0; j < 16; ++j) c += (kx[j] >= cand) ? 1 : 0;
    #pragma unroll
    for (int off = 32; off > 0; off >>= 1) c += __shfl_xor(c, off);
    if (c >= TOPK) pref = cand;
  }
  float invS = 1.0f / S;
  #pragma unroll
  for (int c = 0; c < 4; ++c){
    U4 o;
    float sc[4];
    #pragma unroll
    for (int j = 0; j < 4; ++j){
      int jj = c*4 + j;
      sc[j] = (kx[jj] >= pref) ? expf(v[jj] - M) * invS : 0.f;
    }
    if (WRITE_XS){
      U4 xv = ((const U4*)(xg + row * CDIM))[c * 64 + lane];
      o.x = f2bf(bf2f(xv.x) * sc[0]); o.y = f2bf(bf2f(xv.y) * sc[1]);
      o.z = f2bf(bf2f(xv.z) * sc[2]); o.w = f2bf(bf2f(xv.w) * sc[3]);
    } else {
      o.x = f2bf(sc[0]); o.y = f2bf(sc[1]); o.z = f2bf(sc[2]); o.w = f2bf(sc[3]);
    }
    ((U4*)(obf + row * CDIM))[c * 64 + lane] = o;
  }
}

// ---------------- main dual-A GEMM with fused epilogue ----------------
__global__ __launch_bounds__(256, 3) void k_main(
    const unsigned short* __restrict__ xbf, const unsigned short* __restrict__ xsbf,
    const unsigned short* __restrict__ wt,  const unsigned short* __restrict__ sobf,
    const float* __restrict__ bias, float* __restrict__ out)
{
  __shared__ char lds[2 * 3 * 8192];
  const int tid = threadIdx.x;
  const int lane = tid & 63, w = tid >> 6;
  const int wr = (w >> 1) * 64, wc = (w & 1) * 64;
  // XCD-bijective remap: all 8 col-blocks of a row-panel stay on one XCD.
  // Per-XCD L2 working set: A panels 512 KB (xbf+xsbf) + full W 2 MB < 4 MB.
  int id = blockIdx.x + (blockIdx.y << 3);
  int xcd = id & 7, slot = id >> 3;
  const int row0 = (xcd * 32 + (slot >> 3)) * 128;
  const int col0 = (slot & 7) * 128;
  f32x4 acc1[4][4] = {}, acc2[4][4] = {};
  auto stage = [&](int kt, int buf){
    char* b = lds + buf * 24576;
    stage_tile(xbf  + row0 * CDIM + kt * 32, 2048, b, tid);
    stage_tile(xsbf + row0 * CDIM + kt * 32, 2048, b + 8192, tid);
    stage_tile(wt   + col0 * CDIM + kt * 32, 2048, b + 16384, tid);
  };
  stage(0, 0);
  const int NK = CDIM / 32;
  for (int kt = 0; kt < NK; ++kt){
    __syncthreads();
    if (kt + 1 < NK) stage(kt + 1, (kt & 1) ^ 1);
    const char* b = lds + (kt & 1) * 24576;
    short8 a1[4], a2[4], bb[4];
    #pragma unroll
    for (int m = 0; m < 4; ++m){
      int ra = wr + m * 16 + (lane & 15);
      int rb = wc + m * 16 + (lane & 15);
      a1[m] = frag_ld(b,         ra, lane);
      a2[m] = frag_ld(b + 8192,  ra, lane);
      bb[m] = frag_ld(b + 16384, rb, lane);
    }
    #pragma unroll
    for (int m = 0; m < 4; ++m)
      #pragma unroll
      for (int n = 0; n < 4; ++n){
        acc1[m][n] = __builtin_amdgcn_mfma_f32_16x16x32_bf16(a1[m], bb[n], acc1[m][n], 0, 0, 0);
        acc2[m][n] = __builtin_amdgcn_mfma_f32_16x16x32_bf16(a2[m], bb[n], acc2[m][n], 0, 0, 0);
      }
  }
  #pragma unroll
  for (int n = 0; n < 4; ++n){
    int col = col0 + wc + n * 16 + (lane & 15);
    float bv = bias[col];
    #pragma unroll
    for (int m = 0; m < 4; ++m){
      int row = row0 + wr + m * 16 + ((lane >> 4) << 2);
      #pragma unroll
      for (int r = 0; r < 4; ++r){
        float so = bf2f(sobf[(row + r) * CDIM + col]);
        out[(row + r) * CDIM + col] = acc1[m][n][r] * so + acc2[m][n][r] + bv;
      }
    }
  }
}

extern "C" void kernel_launch(void* const* d_in, const int* in_sizes, int n_in,
                              void* d_out, int out_size, void* d_ws, size_t ws_size,
                              hipStream_t stream)
{
  const float* x    = (const float*)d_in[0];
  const float* W    = (const float*)d_in[1];
  const float* bias = (const float*)d_in[2];
  const float* cwo  = (const float*)d_in[3];
  const float* cbo  = (const float*)d_in[4];
  const float* bngo = (const float*)d_in[5];
  const float* bnbo = (const float*)d_in[6];
  const float* bnmo = (const float*)d_in[7];
  const float* bnvo = (const float*)d_in[8];
  const float* ewo  = (const float*)d_in[9];
  const float* ebo  = (const float*)d_in[10];
  const float* cwi  = (const float*)d_in[11];
  const float* cbi  = (const float*)d_in[12];
  const float* bngi = (const float*)d_in[13];
  const float* bnbi = (const float*)d_in[14];
  const float* bnmi = (const float*)d_in[15];
  const float* bnvi = (const float*)d_in[16];
  const float* ewi  = (const float*)d_in[17];
  const float* ebi  = (const float*)d_in[18];
  float* out = (float*)d_out;
  (void)in_sizes; (void)n_in; (void)out_size; (void)ws_size;

  char* ws = (char*)d_ws;
  size_t off = 0;
  auto alloc = [&](size_t bytes){ void* p = ws + off; off += (bytes + 255) & ~(size_t)255; return p; };
  unsigned short* xbf  = (unsigned short*)alloc((size_t)NROWS * CDIM * 2);
  unsigned short* xsbf = (unsigned short*)alloc((size_t)NROWS * CDIM * 2);
  unsigned short* sobf = (unsigned short*)alloc((size_t)NROWS * CDIM * 2);
  float*          Lbuf = (float*)         alloc((size_t)NROWS * CDIM * 4);
  unsigned short* uho  = (unsigned short*)alloc((size_t)NROWS * BNC * 2);
  unsigned short* ulo  = (unsigned short*)alloc((size_t)NROWS * BNC * 2);
  unsigned short* uhi  = (unsigned short*)alloc((size_t)NROWS * BNC * 2);
  unsigned short* uli  = (unsigned short*)alloc((size_t)NROWS * BNC * 2);
  unsigned short* wtb  = (unsigned short*)alloc((size_t)CDIM * CDIM * 2);
  unsigned short* ewho = (unsigned short*)alloc((size_t)CDIM * BNC * 2);
  unsigned short* ewlo = (unsigned short*)alloc((size_t)CDIM * BNC * 2);
  unsigned short* ewhi = (unsigned short*)alloc((size_t)CDIM * BNC * 2);
  unsigned short* ewli = (unsigned short*)alloc((size_t)CDIM * BNC * 2);

  k_wt<<<dim3(32, 32), dim3(32, 8), 0, stream>>>(W, wtb);
  k_split<<<dim3(1024), dim3(256), 0, stream>>>(ewo, ewho, ewlo, CDIM * BNC);
  k_split<<<dim3(1024), dim3(256), 0, stream>>>(ewi, ewhi, ewli, CDIM * BNC);
  k_bottleneck<<<dim3(NROWS / 8), dim3(256), 0, stream>>>(
      x, cwo, cbo, bngo, bnbo, bnmo, bnvo,
      cwi, cbi, bngi, bnbi, bnmi, bnvi, xbf, uho, ulo, uhi, uli);
  k_expand<<<dim3(8, 256), dim3(256), 0, stream>>>(uho, ulo, ewho, ewlo, ebo, Lbuf);
  k_select<false><<<dim3(NROWS / 4), dim3(256), 0, stream>>>(Lbuf, nullptr, sobf);
  k_expand<<<dim3(8, 256), dim3(256), 0, stream>>>(uhi, uli, ewhi, ewli, ebi, Lbuf);
  k_select<true><<<dim3(NROWS / 4), dim3(256), 0, stream>>>(Lbuf, xbf, xsbf);
  k_main<<<dim3(8, 256), dim3(256), 0, stream>>>(xbf, xsbf, wtb, sobf, bias, out);
}

// Round 3
// 509.515 us; speedup vs baseline: 1.1974x; 1.1974x over previous
//
#include <hip/hip_runtime.h>
#include <hip/hip_bf16.h>

typedef __attribute__((ext_vector_type(8))) short short8;
typedef __attribute__((ext_vector_type(8))) _Float16 half8;
typedef __attribute__((ext_vector_type(4))) float f32x4;

#define NROWS 32768
#define CDIM 1024
#define BNC 256
#define TOPK 128

struct alignas(8) U4 { unsigned short x, y, z, w; };

__device__ __forceinline__ unsigned short f2bf(float f){
  union { float f; unsigned u; } v; v.f = f;
  unsigned r = v.u + 0x7FFFu + ((v.u >> 16) & 1u);
  return (unsigned short)(r >> 16);
}
__device__ __forceinline__ float bf2f(unsigned short h){
  union { unsigned u; float f; } v; v.u = ((unsigned)h) << 16;
  return v.f;
}
__device__ __forceinline__ unsigned short f2h(float f){
  _Float16 h = (_Float16)f;
  union { _Float16 h; unsigned short u; } v; v.h = h; return v.u;
}
__device__ __forceinline__ void gl16(const void* g, void* l){
  __builtin_amdgcn_global_load_lds((const __attribute__((address_space(1))) void*)g,
                                   (__attribute__((address_space(3))) void*)l, 16, 0, 0);
}
// XOR swizzle within a [128 rows][64 bytes] tile. Granule (16B slot) index g (bits
// [5:4]) is XORed with (r&3)^((r>>2)&1) so that a 16-lane frag read (16 rows, same
// k-granule) spreads 2 lanes per bank-quad = free 2-way. Involution (row bits
// untouched) -> apply to global source at stage, and to LDS offset at read.
__device__ __forceinline__ int swzf(int r){ return (r & 3) ^ ((r >> 2) & 1); }
__device__ __forceinline__ int swz(int o){ return o ^ (swzf(o >> 6) << 4); }

// stage one [128 rows][32 k] bf16/fp16 tile (8 KB) into LDS (linear dest, pre-swizzled src)
__device__ __forceinline__ void stage_tile(const unsigned short* g0, int gstride,
                                           char* lds, int tid){
  #pragma unroll
  for (int i = 0; i < 2; ++i){
    int o = tid * 16 + i * 4096;
    int lb = swz(o);
    gl16((const char*)g0 + (lb >> 6) * gstride + (lb & 63), lds + o);
  }
}
__device__ __forceinline__ int frag_off(int ridx, int lane){
  return ridx * 64 + (((lane >> 4) ^ swzf(ridx)) << 4);
}
__device__ __forceinline__ short8 frag_ld(const char* lds, int ridx, int lane){
  return *(const short8*)(lds + frag_off(ridx, lane));
}
__device__ __forceinline__ half8 frag_ld_h(const char* lds, int ridx, int lane){
  return *(const half8*)(lds + frag_off(ridx, lane));
}

// ---------------- param prep ----------------
__global__ void k_wt(const float* __restrict__ W, unsigned short* __restrict__ Wt){
  __shared__ float t[32][33];
  int tx = threadIdx.x, ty = threadIdx.y;
  int bx = blockIdx.x * 32, by = blockIdx.y * 32;
  for (int i = ty; i < 32; i += 8)
    t[i][tx] = W[(by + i) * CDIM + bx + tx];
  __syncthreads();
  for (int i = ty; i < 32; i += 8)
    Wt[(bx + i) * CDIM + by + tx] = f2bf(t[tx][i]);
}

__global__ void k_ecast(const float* __restrict__ eo, const float* __restrict__ ei,
                        unsigned short* __restrict__ ho, unsigned short* __restrict__ hi){
  int i = blockIdx.x * 256 + threadIdx.x;
  ho[i] = f2h(eo[i]);
  hi[i] = f2h(ei[i]);
}

// ---------------- bottleneck: grouped conv + BN + GELU (fp16 out), plus x->bf16 ----------------
__global__ __launch_bounds__(256) void k_bottleneck(
    const float* __restrict__ x,
    const float* __restrict__ cwo, const float* __restrict__ cbo,
    const float* __restrict__ go,  const float* __restrict__ bto,
    const float* __restrict__ mo,  const float* __restrict__ vo,
    const float* __restrict__ cwi, const float* __restrict__ cbi,
    const float* __restrict__ gi,  const float* __restrict__ bti,
    const float* __restrict__ mi,  const float* __restrict__ vi,
    unsigned short* __restrict__ xbf,
    unsigned short* __restrict__ uo, unsigned short* __restrict__ ui)
{
  const int t = threadIdx.x;
  const int r0 = blockIdx.x * 8;
  float4 cwov = ((const float4*)cwo)[t];
  float4 cwiv = ((const float4*)cwi)[t];
  float sco = go[t] * rsqrtf(vo[t] + 1e-5f);
  float sho = bto[t] - mo[t] * sco;
  float cbov = cbo[t];
  float sci = gi[t] * rsqrtf(vi[t] + 1e-5f);
  float shi = bti[t] - mi[t] * sci;
  float cbiv = cbi[t];
  for (int r = 0; r < 8; ++r){
    int row = r0 + r;
    float4 xv = ((const float4*)x)[row * 256 + t];
    U4 xb; xb.x = f2bf(xv.x); xb.y = f2bf(xv.y); xb.z = f2bf(xv.z); xb.w = f2bf(xv.w);
    ((U4*)xbf)[row * 256 + t] = xb;
    float h = xv.x*cwov.x + xv.y*cwov.y + xv.z*cwov.z + xv.w*cwov.w + cbov;
    h = h * sco + sho;
    float u = 0.5f * h * (1.0f + erff(h * 0.70710678118654752f));
    uo[row*BNC + t] = f2h(u);
    h = xv.x*cwiv.x + xv.y*cwiv.y + xv.z*cwiv.z + xv.w*cwiv.w + cbiv;
    h = h * sci + shi;
    u = 0.5f * h * (1.0f + erff(h * 0.70710678118654752f));
    ui[row*BNC + t] = f2h(u);
  }
}

// ---------------- expand GEMM (fp16): L = U@E^T + eb ----------------
__global__ __launch_bounds__(256, 3) void k_expand(
    const unsigned short* __restrict__ u16, const unsigned short* __restrict__ e16,
    const float* __restrict__ eb, float* __restrict__ Lout)
{
  __shared__ char lds[2 * 2 * 8192];
  const int tid = threadIdx.x;
  const int lane = tid & 63, w = tid >> 6;
  const int wr = (w >> 1) * 64, wc = (w & 1) * 64;
  // XCD-bijective remap: all 8 col-blocks of a row-panel stay on one XCD
  int id = blockIdx.x + (blockIdx.y << 3);
  int xcd = id & 7, slot = id >> 3;
  const int row0 = (xcd * 32 + (slot >> 3)) * 128;
  const int col0 = (slot & 7) * 128;
  f32x4 acc[4][4] = {};
  auto stage = [&](int kt, int buf){
    char* b = lds + buf * 16384;
    stage_tile(u16 + row0 * BNC + kt * 32, 512, b, tid);
    stage_tile(e16 + col0 * BNC + kt * 32, 512, b + 8192, tid);
  };
  stage(0, 0);
  const int NK = BNC / 32;
  for (int kt = 0; kt < NK; ++kt){
    __syncthreads();
    if (kt + 1 < NK) stage(kt + 1, (kt & 1) ^ 1);
    const char* b = lds + (kt & 1) * 16384;
    half8 ah[4], bh[4];
    #pragma unroll
    for (int m = 0; m < 4; ++m){
      ah[m] = frag_ld_h(b,        wr + m * 16 + (lane & 15), lane);
      bh[m] = frag_ld_h(b + 8192, wc + m * 16 + (lane & 15), lane);
    }
    #pragma unroll
    for (int m = 0; m < 4; ++m)
      #pragma unroll
      for (int n = 0; n < 4; ++n)
        acc[m][n] = __builtin_amdgcn_mfma_f32_16x16x32_f16(ah[m], bh[n], acc[m][n], 0, 0, 0);
  }
  #pragma unroll
  for (int n = 0; n < 4; ++n){
    int col = col0 + wc + n * 16 + (lane & 15);
    float ebv = eb[col];
    #pragma unroll
    for (int m = 0; m < 4; ++m){
      int row = row0 + wr + m * 16 + ((lane >> 4) << 2);
      #pragma unroll
      for (int r = 0; r < 4; ++r)
        Lout[(row + r) * CDIM + col] = acc[m][n][r] + ebv;
    }
  }
}

// ---------------- softmax + top-128 threshold + sparse score ----------------
template<bool WRITE_XS>
__global__ __launch_bounds__(256) void k_select(
    const float* __restrict__ Lg, const unsigned short* __restrict__ xg,
    unsigned short* __restrict__ obf)
{
  const int lane = threadIdx.x & 63;
  const int row = blockIdx.x * 4 + (threadIdx.x >> 6);
  const float* Lr = Lg + row * CDIM;
  float v[16];
  #pragma unroll
  for (int c = 0; c < 4; ++c){
    float4 t4 = ((const float4*)Lr)[c * 64 + lane];
    v[c*4+0] = t4.x; v[c*4+1] = t4.y; v[c*4+2] = t4.z; v[c*4+3] = t4.w;
  }
  float M = v[0];
  #pragma unroll
  for (int j = 1; j < 16; ++j) M = fmaxf(M, v[j]);
  #pragma unroll
  for (int off = 32; off > 0; off >>= 1) M = fmaxf(M, __shfl_xor(M, off));
  float S = 0.f;
  #pragma unroll
  for (int j = 0; j < 16; ++j) S += expf(v[j] - M);
  #pragma unroll
  for (int off = 32; off > 0; off >>= 1) S += __shfl_xor(S, off);
  unsigned kx[16];
  #pragma unroll
  for (int j = 0; j < 16; ++j){
    union { float f; unsigned u; } q; q.f = v[j];
    kx[j] = q.u ^ ((q.u & 0x80000000u) ? 0xFFFFFFFFu : 0x80000000u);
  }
  unsigned pref = 0;
  for (int bit = 31; bit >= 0; --bit){
    unsigned cand = pref | (1u << bit);
    int c = 0;
    #pragma unroll
    for (int j = 0; j < 16; ++j) c += (kx[j] >= cand) ? 1 : 0;
    #pragma unroll
    for (int off = 32; off > 0; off >>= 1) c += __shfl_xor(c, off);
    if (c >= TOPK) pref = cand;
  }
  float invS = 1.0f / S;
  #pragma unroll
  for (int c = 0; c < 4; ++c){
    U4 o;
    float sc[4];
    #pragma unroll
    for (int j = 0; j < 4; ++j){
      int jj = c*4 + j;
      sc[j] = (kx[jj] >= pref) ? expf(v[jj] - M) * invS : 0.f;
    }
    if (WRITE_XS){
      U4 xv = ((const U4*)(xg + row * CDIM))[c * 64 + lane];
      o.x = f2bf(bf2f(xv.x) * sc[0]); o.y = f2bf(bf2f(xv.y) * sc[1]);
      o.z = f2bf(bf2f(xv.z) * sc[2]); o.w = f2bf(bf2f(xv.w) * sc[3]);
    } else {
      o.x = f2bf(sc[0]); o.y = f2bf(sc[1]); o.z = f2bf(sc[2]); o.w = f2bf(sc[3]);
    }
    ((U4*)(obf + row * CDIM))[c * 64 + lane] = o;
  }
}

// ---------------- main dual-A GEMM with fused epilogue ----------------
__global__ __launch_bounds__(256, 3) void k_main(
    const unsigned short* __restrict__ xbf, const unsigned short* __restrict__ xsbf,
    const unsigned short* __restrict__ wt,  const unsigned short* __restrict__ sobf,
    const float* __restrict__ bias, float* __restrict__ out)
{
  __shared__ char lds[2 * 3 * 8192];
  const int tid = threadIdx.x;
  const int lane = tid & 63, w = tid >> 6;
  const int wr = (w >> 1) * 64, wc = (w & 1) * 64;
  // XCD-bijective remap: all 8 col-blocks of a row-panel stay on one XCD.
  int id = blockIdx.x + (blockIdx.y << 3);
  int xcd = id & 7, slot = id >> 3;
  const int row0 = (xcd * 32 + (slot >> 3)) * 128;
  const int col0 = (slot & 7) * 128;
  f32x4 acc1[4][4] = {}, acc2[4][4] = {};
  auto stage = [&](int kt, int buf){
    char* b = lds + buf * 24576;
    stage_tile(xbf  + row0 * CDIM + kt * 32, 2048, b, tid);
    stage_tile(xsbf + row0 * CDIM + kt * 32, 2048, b + 8192, tid);
    stage_tile(wt   + col0 * CDIM + kt * 32, 2048, b + 16384, tid);
  };
  stage(0, 0);
  const int NK = CDIM / 32;
  for (int kt = 0; kt < NK; ++kt){
    __syncthreads();
    if (kt + 1 < NK) stage(kt + 1, (kt & 1) ^ 1);
    const char* b = lds + (kt & 1) * 24576;
    short8 a1[4], a2[4], bb[4];
    #pragma unroll
    for (int m = 0; m < 4; ++m){
      int ra = wr + m * 16 + (lane & 15);
      int rb = wc + m * 16 + (lane & 15);
      a1[m] = frag_ld(b,         ra, lane);
      a2[m] = frag_ld(b + 8192,  ra, lane);
      bb[m] = frag_ld(b + 16384, rb, lane);
    }
    #pragma unroll
    for (int m = 0; m < 4; ++m)
      #pragma unroll
      for (int n = 0; n < 4; ++n){
        acc1[m][n] = __builtin_amdgcn_mfma_f32_16x16x32_bf16(a1[m], bb[n], acc1[m][n], 0, 0, 0);
        acc2[m][n] = __builtin_amdgcn_mfma_f32_16x16x32_bf16(a2[m], bb[n], acc2[m][n], 0, 0, 0);
      }
  }
  #pragma unroll
  for (int n = 0; n < 4; ++n){
    int col = col0 + wc + n * 16 + (lane & 15);
    float bv = bias[col];
    #pragma unroll
    for (int m = 0; m < 4; ++m){
      int row = row0 + wr + m * 16 + ((lane >> 4) << 2);
      #pragma unroll
      for (int r = 0; r < 4; ++r){
        float so = bf2f(sobf[(row + r) * CDIM + col]);
        out[(row + r) * CDIM + col] = acc1[m][n][r] * so + acc2[m][n][r] + bv;
      }
    }
  }
}

extern "C" void kernel_launch(void* const* d_in, const int* in_sizes, int n_in,
                              void* d_out, int out_size, void* d_ws, size_t ws_size,
                              hipStream_t stream)
{
  const float* x    = (const float*)d_in[0];
  const float* W    = (const float*)d_in[1];
  const float* bias = (const float*)d_in[2];
  const float* cwo  = (const float*)d_in[3];
  const float* cbo  = (const float*)d_in[4];
  const float* bngo = (const float*)d_in[5];
  const float* bnbo = (const float*)d_in[6];
  const float* bnmo = (const float*)d_in[7];
  const float* bnvo = (const float*)d_in[8];
  const float* ewo  = (const float*)d_in[9];
  const float* ebo  = (const float*)d_in[10];
  const float* cwi  = (const float*)d_in[11];
  const float* cbi  = (const float*)d_in[12];
  const float* bngi = (const float*)d_in[13];
  const float* bnbi = (const float*)d_in[14];
  const float* bnmi = (const float*)d_in[15];
  const float* bnvi = (const float*)d_in[16];
  const float* ewi  = (const float*)d_in[17];
  const float* ebi  = (const float*)d_in[18];
  float* out = (float*)d_out;
  (void)in_sizes; (void)n_in; (void)out_size; (void)ws_size;

  char* ws = (char*)d_ws;
  size_t off = 0;
  auto alloc = [&](size_t bytes){ void* p = ws + off; off += (bytes + 255) & ~(size_t)255; return p; };
  unsigned short* xbf  = (unsigned short*)alloc((size_t)NROWS * CDIM * 2);
  unsigned short* xsbf = (unsigned short*)alloc((size_t)NROWS * CDIM * 2);
  unsigned short* sobf = (unsigned short*)alloc((size_t)NROWS * CDIM * 2);
  float*          Lbuf = (float*)         alloc((size_t)NROWS * CDIM * 4);
  unsigned short* uo   = (unsigned short*)alloc((size_t)NROWS * BNC * 2);
  unsigned short* ui   = (unsigned short*)alloc((size_t)NROWS * BNC * 2);
  unsigned short* wtb  = (unsigned short*)alloc((size_t)CDIM * CDIM * 2);
  unsigned short* e16o = (unsigned short*)alloc((size_t)CDIM * BNC * 2);
  unsigned short* e16i = (unsigned short*)alloc((size_t)CDIM * BNC * 2);

  k_wt<<<dim3(32, 32), dim3(32, 8), 0, stream>>>(W, wtb);
  k_ecast<<<dim3(1024), dim3(256), 0, stream>>>(ewo, ewi, e16o, e16i);
  k_bottleneck<<<dim3(NROWS / 8), dim3(256), 0, stream>>>(
      x, cwo, cbo, bngo, bnbo, bnmo, bnvo,
      cwi, cbi, bngi, bnbi, bnmi, bnvi, xbf, uo, ui);
  k_expand<<<dim3(8, 256), dim3(256), 0, stream>>>(uo, e16o, ebo, Lbuf);
  k_select<false><<<dim3(NROWS / 4), dim3(256), 0, stream>>>(Lbuf, nullptr, sobf);
  k_expand<<<dim3(8, 256), dim3(256), 0, stream>>>(ui, e16i, ebi, Lbuf);
  k_select<true><<<dim3(NROWS / 4), dim3(256), 0, stream>>>(Lbuf, xbf, xsbf);
  k_main<<<dim3(8, 256), dim3(256), 0, stream>>>(xbf, xsbf, wtb, sobf, bias, out);
}

// Round 4
// 485.997 us; speedup vs baseline: 1.2554x; 1.0484x over previous
//
#include <hip/hip_runtime.h>
#include <hip/hip_bf16.h>

typedef __attribute__((ext_vector_type(8))) short short8;
typedef __attribute__((ext_vector_type(8))) _Float16 half8;
typedef __attribute__((ext_vector_type(4))) float f32x4;

#define NROWS 32768
#define CDIM 1024
#define BNC 256
#define TOPK 128

struct alignas(8) U4 { unsigned short x, y, z, w; };

__device__ __forceinline__ unsigned short f2bf(float f){
  union { float f; unsigned u; } v; v.f = f;
  unsigned r = v.u + 0x7FFFu + ((v.u >> 16) & 1u);
  return (unsigned short)(r >> 16);
}
__device__ __forceinline__ float bf2f(unsigned short h){
  union { unsigned u; float f; } v; v.u = ((unsigned)h) << 16;
  return v.f;
}
__device__ __forceinline__ unsigned short f2h(float f){
  _Float16 h = (_Float16)f;
  union { _Float16 h; unsigned short u; } v; v.h = h; return v.u;
}
__device__ __forceinline__ void gl16(const void* g, void* l){
  __builtin_amdgcn_global_load_lds((const __attribute__((address_space(1))) void*)g,
                                   (__attribute__((address_space(3))) void*)l, 16, 0, 0);
}
// XOR swizzle within rows of 64B (4 granules of 16B): granule g -> g ^ swzf(r).
// Involution: pre-swizzle global source at stage, swizzle offset at read.
__device__ __forceinline__ int swzf(int r){ return (r & 3) ^ ((r >> 2) & 1); }
__device__ __forceinline__ int swz(int o){ return o ^ (swzf(o >> 6) << 4); }

// stage one [128 rows][32 k] tile (8 KB) into LDS (256-thread blocks)
__device__ __forceinline__ void stage_tile(const unsigned short* g0, int gstride,
                                           char* lds, int tid){
  #pragma unroll
  for (int i = 0; i < 2; ++i){
    int o = tid * 16 + i * 4096;
    int lb = swz(o);
    gl16((const char*)g0 + (lb >> 6) * gstride + (lb & 63), lds + o);
  }
}
__device__ __forceinline__ int frag_off(int ridx, int lane){
  return ridx * 64 + (((lane >> 4) ^ swzf(ridx)) << 4);
}
__device__ __forceinline__ short8 frag_ld(const char* lds, int ridx, int lane){
  return *(const short8*)(lds + frag_off(ridx, lane));
}
__device__ __forceinline__ half8 frag_ld_h(const char* lds, int ridx, int lane){
  return *(const half8*)(lds + frag_off(ridx, lane));
}

// ---------------- param prep ----------------
__global__ void k_wt(const float* __restrict__ W, unsigned short* __restrict__ Wt){
  __shared__ float t[32][33];
  int tx = threadIdx.x, ty = threadIdx.y;
  int bx = blockIdx.x * 32, by = blockIdx.y * 32;
  for (int i = ty; i < 32; i += 8)
    t[i][tx] = W[(by + i) * CDIM + bx + tx];
  __syncthreads();
  for (int i = ty; i < 32; i += 8)
    Wt[(bx + i) * CDIM + by + tx] = f2bf(t[tx][i]);
}

__global__ void k_ecast(const float* __restrict__ eo, const float* __restrict__ ei,
                        unsigned short* __restrict__ ho, unsigned short* __restrict__ hi){
  int i = blockIdx.x * 256 + threadIdx.x;
  ho[i] = f2h(eo[i]);
  hi[i] = f2h(ei[i]);
}

// ---------------- bottleneck: grouped conv + BN + GELU (fp16 out), plus x->bf16 ----------------
__global__ __launch_bounds__(256) void k_bottleneck(
    const float* __restrict__ x,
    const float* __restrict__ cwo, const float* __restrict__ cbo,
    const float* __restrict__ go,  const float* __restrict__ bto,
    const float* __restrict__ mo,  const float* __restrict__ vo,
    const float* __restrict__ cwi, const float* __restrict__ cbi,
    const float* __restrict__ gi,  const float* __restrict__ bti,
    const float* __restrict__ mi,  const float* __restrict__ vi,
    unsigned short* __restrict__ xbf,
    unsigned short* __restrict__ uo, unsigned short* __restrict__ ui)
{
  const int t = threadIdx.x;
  const int r0 = blockIdx.x * 8;
  float4 cwov = ((const float4*)cwo)[t];
  float4 cwiv = ((const float4*)cwi)[t];
  float sco = go[t] * rsqrtf(vo[t] + 1e-5f);
  float sho = bto[t] - mo[t] * sco;
  float cbov = cbo[t];
  float sci = gi[t] * rsqrtf(vi[t] + 1e-5f);
  float shi = bti[t] - mi[t] * sci;
  float cbiv = cbi[t];
  for (int r = 0; r < 8; ++r){
    int row = r0 + r;
    float4 xv = ((const float4*)x)[row * 256 + t];
    U4 xb; xb.x = f2bf(xv.x); xb.y = f2bf(xv.y); xb.z = f2bf(xv.z); xb.w = f2bf(xv.w);
    ((U4*)xbf)[row * 256 + t] = xb;
    float h = xv.x*cwov.x + xv.y*cwov.y + xv.z*cwov.z + xv.w*cwov.w + cbov;
    h = h * sco + sho;
    float u = 0.5f * h * (1.0f + erff(h * 0.70710678118654752f));
    uo[row*BNC + t] = f2h(u);
    h = xv.x*cwiv.x + xv.y*cwiv.y + xv.z*cwiv.z + xv.w*cwiv.w + cbiv;
    h = h * sci + shi;
    u = 0.5f * h * (1.0f + erff(h * 0.70710678118654752f));
    ui[row*BNC + t] = f2h(u);
  }
}

// ---------------- expand GEMM (fp16): L = U@E^T + eb ----------------
__global__ __launch_bounds__(256, 3) void k_expand(
    const unsigned short* __restrict__ u16, const unsigned short* __restrict__ e16,
    const float* __restrict__ eb, float* __restrict__ Lout)
{
  __shared__ char lds[2 * 2 * 8192];
  const int tid = threadIdx.x;
  const int lane = tid & 63, w = tid >> 6;
  const int wr = (w >> 1) * 64, wc = (w & 1) * 64;
  int id = blockIdx.x + (blockIdx.y << 3);
  int xcd = id & 7, slot = id >> 3;
  const int row0 = (xcd * 32 + (slot >> 3)) * 128;
  const int col0 = (slot & 7) * 128;
  f32x4 acc[4][4] = {};
  auto stage = [&](int kt, int buf){
    char* b = lds + buf * 16384;
    stage_tile(u16 + row0 * BNC + kt * 32, 512, b, tid);
    stage_tile(e16 + col0 * BNC + kt * 32, 512, b + 8192, tid);
  };
  stage(0, 0);
  const int NK = BNC / 32;
  for (int kt = 0; kt < NK; ++kt){
    __syncthreads();
    if (kt + 1 < NK) stage(kt + 1, (kt & 1) ^ 1);
    const char* b = lds + (kt & 1) * 16384;
    half8 ah[4], bh[4];
    #pragma unroll
    for (int m = 0; m < 4; ++m){
      ah[m] = frag_ld_h(b,        wr + m * 16 + (lane & 15), lane);
      bh[m] = frag_ld_h(b + 8192, wc + m * 16 + (lane & 15), lane);
    }
    #pragma unroll
    for (int m = 0; m < 4; ++m)
      #pragma unroll
      for (int n = 0; n < 4; ++n)
        acc[m][n] = __builtin_amdgcn_mfma_f32_16x16x32_f16(ah[m], bh[n], acc[m][n], 0, 0, 0);
  }
  #pragma unroll
  for (int n = 0; n < 4; ++n){
    int col = col0 + wc + n * 16 + (lane & 15);
    float ebv = eb[col];
    #pragma unroll
    for (int m = 0; m < 4; ++m){
      int row = row0 + wr + m * 16 + ((lane >> 4) << 2);
      #pragma unroll
      for (int r = 0; r < 4; ++r)
        Lout[(row + r) * CDIM + col] = acc[m][n][r] + ebv;
    }
  }
}

// ---------------- softmax + top-128 threshold + sparse score ----------------
template<bool WRITE_XS>
__global__ __launch_bounds__(256) void k_select(
    const float* __restrict__ Lg, const unsigned short* __restrict__ xg,
    unsigned short* __restrict__ obf)
{
  const int lane = threadIdx.x & 63;
  const int row = blockIdx.x * 4 + (threadIdx.x >> 6);
  const float* Lr = Lg + row * CDIM;
  float v[16];
  #pragma unroll
  for (int c = 0; c < 4; ++c){
    float4 t4 = ((const float4*)Lr)[c * 64 + lane];
    v[c*4+0] = t4.x; v[c*4+1] = t4.y; v[c*4+2] = t4.z; v[c*4+3] = t4.w;
  }
  float M = v[0];
  #pragma unroll
  for (int j = 1; j < 16; ++j) M = fmaxf(M, v[j]);
  #pragma unroll
  for (int off = 32; off > 0; off >>= 1) M = fmaxf(M, __shfl_xor(M, off));
  float S = 0.f;
  #pragma unroll
  for (int j = 0; j < 16; ++j) S += expf(v[j] - M);
  #pragma unroll
  for (int off = 32; off > 0; off >>= 1) S += __shfl_xor(S, off);
  unsigned kx[16];
  #pragma unroll
  for (int j = 0; j < 16; ++j){
    union { float f; unsigned u; } q; q.f = v[j];
    kx[j] = q.u ^ ((q.u & 0x80000000u) ? 0xFFFFFFFFu : 0x80000000u);
  }
  unsigned pref = 0;
  for (int bit = 31; bit >= 0; --bit){
    unsigned cand = pref | (1u << bit);
    int c = 0;
    #pragma unroll
    for (int j = 0; j < 16; ++j) c += (kx[j] >= cand) ? 1 : 0;
    #pragma unroll
    for (int off = 32; off > 0; off >>= 1) c += __shfl_xor(c, off);
    if (c >= TOPK) pref = cand;
  }
  float invS = 1.0f / S;
  #pragma unroll
  for (int c = 0; c < 4; ++c){
    U4 o;
    float sc[4];
    #pragma unroll
    for (int j = 0; j < 4; ++j){
      int jj = c*4 + j;
      sc[j] = (kx[jj] >= pref) ? expf(v[jj] - M) * invS : 0.f;
    }
    if (WRITE_XS){
      U4 xv = ((const U4*)(xg + row * CDIM))[c * 64 + lane];
      o.x = f2bf(bf2f(xv.x) * sc[0]); o.y = f2bf(bf2f(xv.y) * sc[1]);
      o.z = f2bf(bf2f(xv.z) * sc[2]); o.w = f2bf(bf2f(xv.w) * sc[3]);
    } else {
      o.x = f2bf(sc[0]); o.y = f2bf(sc[1]); o.z = f2bf(sc[2]); o.w = f2bf(sc[3]);
    }
    ((U4*)(obf + row * CDIM))[c * 64 + lane] = o;
  }
}

// ---------------- main dual-A GEMM: counted-vmcnt half-tile pipeline ----------------
// 512 thr / 8 waves, tile 128x256, half-tile quantum = 32 k-cols (A1 8K + A2 8K + B 16K
// = 32 KB), 3 LDS slots rotating h%3, stage h+2 during h, vmcnt(4) once per half-tile.
#define KMAIN_H (CDIM / 32)

__device__ __forceinline__ void km_stageA(const unsigned short* a1, const unsigned short* a2,
                                          int row0, int h, char* slot, int tid){
  int o = tid * 16;
  int r = o >> 6;
  int gs = ((o >> 4) & 3) ^ swzf(r);
  size_t src = (size_t)(row0 + r) * (CDIM * 2) + h * 64 + gs * 16;
  gl16((const char*)a1 + src, slot + o);
  gl16((const char*)a2 + src, slot + 8192 + o);
}
__device__ __forceinline__ void km_stageB(const unsigned short* wt, int col0, int h,
                                          char* slot, int tid){
  #pragma unroll
  for (int i = 0; i < 2; ++i){
    int o = i * 8192 + tid * 16;
    int r = o >> 6;
    int gs = ((o >> 4) & 3) ^ swzf(r);
    gl16((const char*)wt + (size_t)(col0 + r) * (CDIM * 2) + h * 64 + gs * 16,
         slot + 16384 + o);
  }
}

__global__ __launch_bounds__(512, 2) void k_main(
    const unsigned short* __restrict__ xbf, const unsigned short* __restrict__ xsbf,
    const unsigned short* __restrict__ wt,  const unsigned short* __restrict__ sobf,
    const float* __restrict__ bias, float* __restrict__ out)
{
  __shared__ alignas(16) char lds[3 * 32768];
  const int tid = threadIdx.x;
  const int lane = tid & 63, wid = tid >> 6;
  const int wrow = (wid >> 2) * 64, wcol = (wid & 3) * 64;
  // XCD-bijective remap: 4 col-blocks of a row-panel consecutive on one XCD
  int id = blockIdx.x;
  int xcd = id & 7, slot_ = id >> 3;
  const int row0 = (xcd * 32 + (slot_ >> 2)) * 128;
  const int col0 = (slot_ & 3) * 256;
  f32x4 acc1[4][4] = {}, acc2[4][4] = {};

  km_stageA(xbf, xsbf, row0, 0, lds, tid);
  km_stageB(wt, col0, 0, lds, tid);
  km_stageA(xbf, xsbf, row0, 1, lds + 32768, tid);
  km_stageB(wt, col0, 1, lds + 32768, tid);
  asm volatile("s_waitcnt vmcnt(4)" ::: "memory");
  __builtin_amdgcn_s_barrier();
  asm volatile("" ::: "memory");

  for (int h = 0; h < KMAIN_H; ++h){
    char* sl = lds + (h % 3) * 32768;
    char* sp = lds + ((h + 2) % 3) * 32768;
    short8 a1f[4], a2f[4], bf[4];
    // ---- phase A: acc1 ----
    #pragma unroll
    for (int m = 0; m < 4; ++m) a1f[m] = frag_ld(sl, wrow + m * 16 + (lane & 15), lane);
    #pragma unroll
    for (int n = 0; n < 4; ++n) bf[n] = frag_ld(sl + 16384, wcol + n * 16 + (lane & 15), lane);
    if (h + 2 < KMAIN_H) km_stageA(xbf, xsbf, row0, h + 2, sp, tid);
    __builtin_amdgcn_s_barrier();
    asm volatile("" ::: "memory");
    __builtin_amdgcn_s_setprio(1);
    #pragma unroll
    for (int m = 0; m < 4; ++m)
      #pragma unroll
      for (int n = 0; n < 4; ++n)
        acc1[m][n] = __builtin_amdgcn_mfma_f32_16x16x32_bf16(a1f[m], bf[n], acc1[m][n], 0, 0, 0);
    __builtin_amdgcn_s_setprio(0);
    __builtin_amdgcn_s_barrier();
    asm volatile("" ::: "memory");
    // ---- phase B: acc2 ----
    #pragma unroll
    for (int m = 0; m < 4; ++m) a2f[m] = frag_ld(sl + 8192, wrow + m * 16 + (lane & 15), lane);
    if (h + 2 < KMAIN_H) km_stageB(wt, col0, h + 2, sp, tid);
    __builtin_amdgcn_s_barrier();
    asm volatile("" ::: "memory");
    __builtin_amdgcn_s_setprio(1);
    #pragma unroll
    for (int m = 0; m < 4; ++m)
      #pragma unroll
      for (int n = 0; n < 4; ++n)
        acc2[m][n] = __builtin_amdgcn_mfma_f32_16x16x32_bf16(a2f[m], bf[n], acc2[m][n], 0, 0, 0);
    __builtin_amdgcn_s_setprio(0);
    // ---- end-of-half-tile counted wait (covers h+1's quanta; keeps h+2's in flight) ----
    if (h + 1 < KMAIN_H){
      if (h + 2 < KMAIN_H) asm volatile("s_waitcnt vmcnt(4)" ::: "memory");
      else                 asm volatile("s_waitcnt vmcnt(0)" ::: "memory");
    }
    __builtin_amdgcn_s_barrier();
    asm volatile("" ::: "memory");
  }

  #pragma unroll
  for (int n = 0; n < 4; ++n){
    int col = col0 + wcol + n * 16 + (lane & 15);
    float bv = bias[col];
    #pragma unroll
    for (int m = 0; m < 4; ++m){
      int row = row0 + wrow + m * 16 + ((lane >> 4) << 2);
      #pragma unroll
      for (int r = 0; r < 4; ++r){
        float so = bf2f(sobf[(size_t)(row + r) * CDIM + col]);
        out[(size_t)(row + r) * CDIM + col] = acc1[m][n][r] * so + acc2[m][n][r] + bv;
      }
    }
  }
}

extern "C" void kernel_launch(void* const* d_in, const int* in_sizes, int n_in,
                              void* d_out, int out_size, void* d_ws, size_t ws_size,
                              hipStream_t stream)
{
  const float* x    = (const float*)d_in[0];
  const float* W    = (const float*)d_in[1];
  const float* bias = (const float*)d_in[2];
  const float* cwo  = (const float*)d_in[3];
  const float* cbo  = (const float*)d_in[4];
  const float* bngo = (const float*)d_in[5];
  const float* bnbo = (const float*)d_in[6];
  const float* bnmo = (const float*)d_in[7];
  const float* bnvo = (const float*)d_in[8];
  const float* ewo  = (const float*)d_in[9];
  const float* ebo  = (const float*)d_in[10];
  const float* cwi  = (const float*)d_in[11];
  const float* cbi  = (const float*)d_in[12];
  const float* bngi = (const float*)d_in[13];
  const float* bnbi = (const float*)d_in[14];
  const float* bnmi = (const float*)d_in[15];
  const float* bnvi = (const float*)d_in[16];
  const float* ewi  = (const float*)d_in[17];
  const float* ebi  = (const float*)d_in[18];
  float* out = (float*)d_out;
  (void)in_sizes; (void)n_in; (void)out_size; (void)ws_size;

  char* ws = (char*)d_ws;
  size_t off = 0;
  auto alloc = [&](size_t bytes){ void* p = ws + off; off += (bytes + 255) & ~(size_t)255; return p; };
  unsigned short* xbf  = (unsigned short*)alloc((size_t)NROWS * CDIM * 2);
  unsigned short* xsbf = (unsigned short*)alloc((size_t)NROWS * CDIM * 2);
  unsigned short* sobf = (unsigned short*)alloc((size_t)NROWS * CDIM * 2);
  float*          Lbuf = (float*)         alloc((size_t)NROWS * CDIM * 4);
  unsigned short* uo   = (unsigned short*)alloc((size_t)NROWS * BNC * 2);
  unsigned short* ui   = (unsigned short*)alloc((size_t)NROWS * BNC * 2);
  unsigned short* wtb  = (unsigned short*)alloc((size_t)CDIM * CDIM * 2);
  unsigned short* e16o = (unsigned short*)alloc((size_t)CDIM * BNC * 2);
  unsigned short* e16i = (unsigned short*)alloc((size_t)CDIM * BNC * 2);

  k_wt<<<dim3(32, 32), dim3(32, 8), 0, stream>>>(W, wtb);
  k_ecast<<<dim3(1024), dim3(256), 0, stream>>>(ewo, ewi, e16o, e16i);
  k_bottleneck<<<dim3(NROWS / 8), dim3(256), 0, stream>>>(
      x, cwo, cbo, bngo, bnbo, bnmo, bnvo,
      cwi, cbi, bngi, bnbi, bnmi, bnvi, xbf, uo, ui);
  k_expand<<<dim3(8, 256), dim3(256), 0, stream>>>(uo, e16o, ebo, Lbuf);
  k_select<false><<<dim3(NROWS / 4), dim3(256), 0, stream>>>(Lbuf, nullptr, sobf);
  k_expand<<<dim3(8, 256), dim3(256), 0, stream>>>(ui, e16i, ebi, Lbuf);
  k_select<true><<<dim3(NROWS / 4), dim3(256), 0, stream>>>(Lbuf, xbf, xsbf);
  k_main<<<dim3(1024), dim3(512), 0, stream>>>(xbf, xsbf, wtb, sobf, bias, out);
}

// Round 5
// 481.824 us; speedup vs baseline: 1.2663x; 1.0087x over previous
//
#include <hip/hip_runtime.h>
#include <hip/hip_bf16.h>

typedef __attribute__((ext_vector_type(8))) short short8;
typedef __attribute__((ext_vector_type(8))) _Float16 half8;
typedef __attribute__((ext_vector_type(4))) float f32x4;

#define NROWS 32768
#define CDIM 1024
#define BNC 256
#define TOPK 128

struct alignas(8) U4 { unsigned short x, y, z, w; };

__device__ __forceinline__ unsigned short f2bf(float f){
  union { float f; unsigned u; } v; v.f = f;
  unsigned r = v.u + 0x7FFFu + ((v.u >> 16) & 1u);
  return (unsigned short)(r >> 16);
}
__device__ __forceinline__ float bf2f(unsigned short h){
  union { unsigned u; float f; } v; v.u = ((unsigned)h) << 16;
  return v.f;
}
__device__ __forceinline__ unsigned short f2h(float f){
  _Float16 h = (_Float16)f;
  union { _Float16 h; unsigned short u; } v; v.h = h; return v.u;
}
__device__ __forceinline__ void gl16(const void* g, void* l){
  __builtin_amdgcn_global_load_lds((const __attribute__((address_space(1))) void*)g,
                                   (__attribute__((address_space(3))) void*)l, 16, 0, 0);
}
__device__ __forceinline__ unsigned ldsaddr(const void* p){
  return (unsigned)(uintptr_t)(const __attribute__((address_space(3))) void*)p;
}
// asm ds_read_b128: invisible to the waitcnt pass -> no auto vmcnt drains against
// outstanding global_load_lds. Correctness: barriers + explicit lgkmcnt(0) +
// sched_barrier(0) before the consuming MFMAs (rule #18).
__device__ __forceinline__ short8 dsr128(unsigned addr){
  short8 r;
  asm volatile("ds_read_b128 %0, %1" : "=v"(r) : "v"(addr));
  return r;
}
__device__ __forceinline__ half8 s2h(short8 s){ union { short8 s; half8 h; } u; u.s = s; return u.h; }

// XOR swizzle within rows of 64B (4 granules of 16B): granule g -> g ^ swzf(r).
// Involution: pre-swizzle global source at stage, swizzle offset at read.
__device__ __forceinline__ int swzf(int r){ return (r & 3) ^ ((r >> 2) & 1); }
__device__ __forceinline__ int swz(int o){ return o ^ (swzf(o >> 6) << 4); }

// stage one [128 rows][32 k] tile (8 KB) into LDS (256-thread blocks)
__device__ __forceinline__ void stage_tile(const unsigned short* g0, int gstride,
                                           char* lds, int tid){
  #pragma unroll
  for (int i = 0; i < 2; ++i){
    int o = tid * 16 + i * 4096;
    int lb = swz(o);
    gl16((const char*)g0 + (lb >> 6) * gstride + (lb & 63), lds + o);
  }
}
__device__ __forceinline__ int frag_off(int ridx, int lane){
  return ridx * 64 + (((lane >> 4) ^ swzf(ridx)) << 4);
}
__device__ __forceinline__ short8 frag_ld(const char* lds, int ridx, int lane){
  return *(const short8*)(lds + frag_off(ridx, lane));
}

// ---------------- param prep ----------------
__global__ void k_wt(const float* __restrict__ W, unsigned short* __restrict__ Wt){
  __shared__ float t[32][33];
  int tx = threadIdx.x, ty = threadIdx.y;
  int bx = blockIdx.x * 32, by = blockIdx.y * 32;
  for (int i = ty; i < 32; i += 8)
    t[i][tx] = W[(by + i) * CDIM + bx + tx];
  __syncthreads();
  for (int i = ty; i < 32; i += 8)
    Wt[(bx + i) * CDIM + by + tx] = f2bf(t[tx][i]);
}

__global__ void k_ecast(const float* __restrict__ eo, const float* __restrict__ ei,
                        unsigned short* __restrict__ ho, unsigned short* __restrict__ hi){
  int i = blockIdx.x * 256 + threadIdx.x;
  ho[i] = f2h(eo[i]);
  hi[i] = f2h(ei[i]);
}

// ---------------- bottleneck: grouped conv + BN + GELU (fp16 out), plus x->bf16 ----------------
__global__ __launch_bounds__(256) void k_bottleneck(
    const float* __restrict__ x,
    const float* __restrict__ cwo, const float* __restrict__ cbo,
    const float* __restrict__ go,  const float* __restrict__ bto,
    const float* __restrict__ mo,  const float* __restrict__ vo,
    const float* __restrict__ cwi, const float* __restrict__ cbi,
    const float* __restrict__ gi,  const float* __restrict__ bti,
    const float* __restrict__ mi,  const float* __restrict__ vi,
    unsigned short* __restrict__ xbf,
    unsigned short* __restrict__ uo, unsigned short* __restrict__ ui)
{
  const int t = threadIdx.x;
  const int r0 = blockIdx.x * 8;
  float4 cwov = ((const float4*)cwo)[t];
  float4 cwiv = ((const float4*)cwi)[t];
  float sco = go[t] * rsqrtf(vo[t] + 1e-5f);
  float sho = bto[t] - mo[t] * sco;
  float cbov = cbo[t];
  float sci = gi[t] * rsqrtf(vi[t] + 1e-5f);
  float shi = bti[t] - mi[t] * sci;
  float cbiv = cbi[t];
  for (int r = 0; r < 8; ++r){
    int row = r0 + r;
    float4 xv = ((const float4*)x)[row * 256 + t];
    U4 xb; xb.x = f2bf(xv.x); xb.y = f2bf(xv.y); xb.z = f2bf(xv.z); xb.w = f2bf(xv.w);
    ((U4*)xbf)[row * 256 + t] = xb;
    float h = xv.x*cwov.x + xv.y*cwov.y + xv.z*cwov.z + xv.w*cwov.w + cbov;
    h = h * sco + sho;
    float u = 0.5f * h * (1.0f + erff(h * 0.70710678118654752f));
    uo[row*BNC + t] = f2h(u);
    h = xv.x*cwiv.x + xv.y*cwiv.y + xv.z*cwiv.z + xv.w*cwiv.w + cbiv;
    h = h * sci + shi;
    u = 0.5f * h * (1.0f + erff(h * 0.70710678118654752f));
    ui[row*BNC + t] = f2h(u);
  }
}

// ---------------- expand GEMM (fp16): L = U@E^T + eb ----------------
// 3-slot counted-vmcnt pipeline, asm ds_read. 128x128 tile, BK=32, 48KB LDS (3 blk/CU).
__global__ __launch_bounds__(256, 3) void k_expand(
    const unsigned short* __restrict__ u16, const unsigned short* __restrict__ e16,
    const float* __restrict__ eb, float* __restrict__ Lout)
{
  __shared__ alignas(16) char lds[3 * 16384];
  const int tid = threadIdx.x;
  const int lane = tid & 63, w = tid >> 6;
  const int wr = (w >> 1) * 64, wc = (w & 1) * 64;
  int id = blockIdx.x;
  int xcd = id & 7, slot = id >> 3;
  const int row0 = (xcd * 32 + (slot >> 3)) * 128;
  const int col0 = (slot & 7) * 128;
  f32x4 acc[4][4] = {};
  auto stage = [&](int h, int buf){
    char* b = lds + buf * 16384;
    stage_tile(u16 + row0 * BNC + h * 32, 512, b, tid);
    stage_tile(e16 + col0 * BNC + h * 32, 512, b + 8192, tid);
  };
  stage(0, 0);
  stage(1, 1);
  asm volatile("s_waitcnt vmcnt(4)" ::: "memory");
  __builtin_amdgcn_s_barrier();
  const unsigned lbase = ldsaddr(lds);
  const int NK = BNC / 32;
  for (int h = 0; h < NK; ++h){
    unsigned sl = lbase + (h % 3) * 16384;
    short8 af[4], bfr[4];
    #pragma unroll
    for (int m = 0; m < 4; ++m) af[m]  = dsr128(sl + frag_off(wr + m * 16 + (lane & 15), lane));
    #pragma unroll
    for (int n = 0; n < 4; ++n) bfr[n] = dsr128(sl + 8192 + frag_off(wc + n * 16 + (lane & 15), lane));
    if (h + 2 < NK) stage(h + 2, (h + 2) % 3);
    __builtin_amdgcn_s_barrier();
    asm volatile("s_waitcnt lgkmcnt(0)" ::: "memory");
    __builtin_amdgcn_sched_barrier(0);
    __builtin_amdgcn_s_setprio(1);
    #pragma unroll
    for (int m = 0; m < 4; ++m)
      #pragma unroll
      for (int n = 0; n < 4; ++n)
        acc[m][n] = __builtin_amdgcn_mfma_f32_16x16x32_f16(s2h(af[m]), s2h(bfr[n]), acc[m][n], 0, 0, 0);
    __builtin_amdgcn_s_setprio(0);
    if (h + 2 < NK)      asm volatile("s_waitcnt vmcnt(4)" ::: "memory");
    else if (h + 1 < NK) asm volatile("s_waitcnt vmcnt(0)" ::: "memory");
    __builtin_amdgcn_s_barrier();
  }
  #pragma unroll
  for (int n = 0; n < 4; ++n){
    int col = col0 + wc + n * 16 + (lane & 15);
    float ebv = eb[col];
    #pragma unroll
    for (int m = 0; m < 4; ++m){
      int row = row0 + wr + m * 16 + ((lane >> 4) << 2);
      #pragma unroll
      for (int r = 0; r < 4; ++r)
        Lout[(row + r) * CDIM + col] = acc[m][n][r] + ebv;
    }
  }
}

// ---------------- softmax + top-128 threshold + sparse score ----------------
template<bool WRITE_XS>
__global__ __launch_bounds__(256) void k_select(
    const float* __restrict__ Lg, const unsigned short* __restrict__ xg,
    unsigned short* __restrict__ obf)
{
  const int lane = threadIdx.x & 63;
  const int row = blockIdx.x * 4 + (threadIdx.x >> 6);
  const float* Lr = Lg + row * CDIM;
  float v[16];
  #pragma unroll
  for (int c = 0; c < 4; ++c){
    float4 t4 = ((const float4*)Lr)[c * 64 + lane];
    v[c*4+0] = t4.x; v[c*4+1] = t4.y; v[c*4+2] = t4.z; v[c*4+3] = t4.w;
  }
  float M = v[0];
  #pragma unroll
  for (int j = 1; j < 16; ++j) M = fmaxf(M, v[j]);
  #pragma unroll
  for (int off = 32; off > 0; off >>= 1) M = fmaxf(M, __shfl_xor(M, off));
  float S = 0.f;
  #pragma unroll
  for (int j = 0; j < 16; ++j) S += expf(v[j] - M);
  #pragma unroll
  for (int off = 32; off > 0; off >>= 1) S += __shfl_xor(S, off);
  unsigned kx[16];
  #pragma unroll
  for (int j = 0; j < 16; ++j){
    union { float f; unsigned u; } q; q.f = v[j];
    kx[j] = q.u ^ ((q.u & 0x80000000u) ? 0xFFFFFFFFu : 0x80000000u);
  }
  unsigned pref = 0;
  for (int bit = 31; bit >= 0; --bit){
    unsigned cand = pref | (1u << bit);
    int c = 0;
    #pragma unroll
    for (int j = 0; j < 16; ++j) c += (kx[j] >= cand) ? 1 : 0;
    #pragma unroll
    for (int off = 32; off > 0; off >>= 1) c += __shfl_xor(c, off);
    if (c >= TOPK) pref = cand;
  }
  float invS = 1.0f / S;
  #pragma unroll
  for (int c = 0; c < 4; ++c){
    U4 o;
    float sc[4];
    #pragma unroll
    for (int j = 0; j < 4; ++j){
      int jj = c*4 + j;
      sc[j] = (kx[jj] >= pref) ? expf(v[jj] - M) * invS : 0.f;
    }
    if (WRITE_XS){
      U4 xv = ((const U4*)(xg + row * CDIM))[c * 64 + lane];
      o.x = f2bf(bf2f(xv.x) * sc[0]); o.y = f2bf(bf2f(xv.y) * sc[1]);
      o.z = f2bf(bf2f(xv.z) * sc[2]); o.w = f2bf(bf2f(xv.w) * sc[3]);
    } else {
      o.x = f2bf(sc[0]); o.y = f2bf(sc[1]); o.z = f2bf(sc[2]); o.w = f2bf(sc[3]);
    }
    ((U4*)(obf + row * CDIM))[c * 64 + lane] = o;
  }
}

// ---------------- main dual-A GEMM: counted-vmcnt half-tile pipeline, asm ds_read ----------------
#define KMAIN_H (CDIM / 32)

__device__ __forceinline__ void km_stageA(const unsigned short* a1, const unsigned short* a2,
                                          int row0, int h, char* slot, int tid){
  int o = tid * 16;
  int r = o >> 6;
  int gs = ((o >> 4) & 3) ^ swzf(r);
  size_t src = (size_t)(row0 + r) * (CDIM * 2) + h * 64 + gs * 16;
  gl16((const char*)a1 + src, slot + o);
  gl16((const char*)a2 + src, slot + 8192 + o);
}
__device__ __forceinline__ void km_stageB(const unsigned short* wt, int col0, int h,
                                          char* slot, int tid){
  #pragma unroll
  for (int i = 0; i < 2; ++i){
    int o = i * 8192 + tid * 16;
    int r = o >> 6;
    int gs = ((o >> 4) & 3) ^ swzf(r);
    gl16((const char*)wt + (size_t)(col0 + r) * (CDIM * 2) + h * 64 + gs * 16,
         slot + 16384 + o);
  }
}

__global__ __launch_bounds__(512, 2) void k_main(
    const unsigned short* __restrict__ xbf, const unsigned short* __restrict__ xsbf,
    const unsigned short* __restrict__ wt,  const unsigned short* __restrict__ sobf,
    const float* __restrict__ bias, float* __restrict__ out)
{
  __shared__ alignas(16) char lds[3 * 32768];
  const int tid = threadIdx.x;
  const int lane = tid & 63, wid = tid >> 6;
  const int wrow = (wid >> 2) * 64, wcol = (wid & 3) * 64;
  int id = blockIdx.x;
  int xcd = id & 7, slot_ = id >> 3;
  const int row0 = (xcd * 32 + (slot_ >> 2)) * 128;
  const int col0 = (slot_ & 3) * 256;
  f32x4 acc1[4][4] = {}, acc2[4][4] = {};

  km_stageA(xbf, xsbf, row0, 0, lds, tid);
  km_stageB(wt, col0, 0, lds, tid);
  km_stageA(xbf, xsbf, row0, 1, lds + 32768, tid);
  km_stageB(wt, col0, 1, lds + 32768, tid);
  asm volatile("s_waitcnt vmcnt(4)" ::: "memory");
  __builtin_amdgcn_s_barrier();
  const unsigned lbase = ldsaddr(lds);

  for (int h = 0; h < KMAIN_H; ++h){
    unsigned sl = lbase + (h % 3) * 32768;
    char* sp = lds + ((h + 2) % 3) * 32768;
    short8 a1f[4], a2f[4], bf[4];
    // ---- phase A: acc1 ----
    #pragma unroll
    for (int m = 0; m < 4; ++m) a1f[m] = dsr128(sl + frag_off(wrow + m * 16 + (lane & 15), lane));
    #pragma unroll
    for (int n = 0; n < 4; ++n) bf[n] = dsr128(sl + 16384 + frag_off(wcol + n * 16 + (lane & 15), lane));
    if (h + 2 < KMAIN_H) km_stageA(xbf, xsbf, row0, h + 2, sp, tid);
    __builtin_amdgcn_s_barrier();
    asm volatile("s_waitcnt lgkmcnt(0)" ::: "memory");
    __builtin_amdgcn_sched_barrier(0);
    __builtin_amdgcn_s_setprio(1);
    #pragma unroll
    for (int m = 0; m < 4; ++m)
      #pragma unroll
      for (int n = 0; n < 4; ++n)
        acc1[m][n] = __builtin_amdgcn_mfma_f32_16x16x32_bf16(a1f[m], bf[n], acc1[m][n], 0, 0, 0);
    __builtin_amdgcn_s_setprio(0);
    __builtin_amdgcn_s_barrier();
    // ---- phase B: acc2 ----
    #pragma unroll
    for (int m = 0; m < 4; ++m) a2f[m] = dsr128(sl + 8192 + frag_off(wrow + m * 16 + (lane & 15), lane));
    if (h + 2 < KMAIN_H) km_stageB(wt, col0, h + 2, sp, tid);
    __builtin_amdgcn_s_barrier();
    asm volatile("s_waitcnt lgkmcnt(0)" ::: "memory");
    __builtin_amdgcn_sched_barrier(0);
    __builtin_amdgcn_s_setprio(1);
    #pragma unroll
    for (int m = 0; m < 4; ++m)
      #pragma unroll
      for (int n = 0; n < 4; ++n)
        acc2[m][n] = __builtin_amdgcn_mfma_f32_16x16x32_bf16(a2f[m], bf[n], acc2[m][n], 0, 0, 0);
    __builtin_amdgcn_s_setprio(0);
    // ---- end-of-half-tile counted wait ----
    if (h + 2 < KMAIN_H)      asm volatile("s_waitcnt vmcnt(4)" ::: "memory");
    else if (h + 1 < KMAIN_H) asm volatile("s_waitcnt vmcnt(0)" ::: "memory");
    __builtin_amdgcn_s_barrier();
  }

  #pragma unroll
  for (int n = 0; n < 4; ++n){
    int col = col0 + wcol + n * 16 + (lane & 15);
    float bv = bias[col];
    #pragma unroll
    for (int m = 0; m < 4; ++m){
      int row = row0 + wrow + m * 16 + ((lane >> 4) << 2);
      #pragma unroll
      for (int r = 0; r < 4; ++r){
        float so = bf2f(sobf[(size_t)(row + r) * CDIM + col]);
        out[(size_t)(row + r) * CDIM + col] = acc1[m][n][r] * so + acc2[m][n][r] + bv;
      }
    }
  }
}

extern "C" void kernel_launch(void* const* d_in, const int* in_sizes, int n_in,
                              void* d_out, int out_size, void* d_ws, size_t ws_size,
                              hipStream_t stream)
{
  const float* x    = (const float*)d_in[0];
  const float* W    = (const float*)d_in[1];
  const float* bias = (const float*)d_in[2];
  const float* cwo  = (const float*)d_in[3];
  const float* cbo  = (const float*)d_in[4];
  const float* bngo = (const float*)d_in[5];
  const float* bnbo = (const float*)d_in[6];
  const float* bnmo = (const float*)d_in[7];
  const float* bnvo = (const float*)d_in[8];
  const float* ewo  = (const float*)d_in[9];
  const float* ebo  = (const float*)d_in[10];
  const float* cwi  = (const float*)d_in[11];
  const float* cbi  = (const float*)d_in[12];
  const float* bngi = (const float*)d_in[13];
  const float* bnbi = (const float*)d_in[14];
  const float* bnmi = (const float*)d_in[15];
  const float* bnvi = (const float*)d_in[16];
  const float* ewi  = (const float*)d_in[17];
  const float* ebi  = (const float*)d_in[18];
  float* out = (float*)d_out;
  (void)in_sizes; (void)n_in; (void)out_size; (void)ws_size;

  char* ws = (char*)d_ws;
  size_t off = 0;
  auto alloc = [&](size_t bytes){ void* p = ws + off; off += (bytes + 255) & ~(size_t)255; return p; };
  unsigned short* xbf  = (unsigned short*)alloc((size_t)NROWS * CDIM * 2);
  unsigned short* xsbf = (unsigned short*)alloc((size_t)NROWS * CDIM * 2);
  unsigned short* sobf = (unsigned short*)alloc((size_t)NROWS * CDIM * 2);
  float*          Lbuf = (float*)         alloc((size_t)NROWS * CDIM * 4);
  unsigned short* uo   = (unsigned short*)alloc((size_t)NROWS * BNC * 2);
  unsigned short* ui   = (unsigned short*)alloc((size_t)NROWS * BNC * 2);
  unsigned short* wtb  = (unsigned short*)alloc((size_t)CDIM * CDIM * 2);
  unsigned short* e16o = (unsigned short*)alloc((size_t)CDIM * BNC * 2);
  unsigned short* e16i = (unsigned short*)alloc((size_t)CDIM * BNC * 2);

  k_wt<<<dim3(32, 32), dim3(32, 8), 0, stream>>>(W, wtb);
  k_ecast<<<dim3(1024), dim3(256), 0, stream>>>(ewo, ewi, e16o, e16i);
  k_bottleneck<<<dim3(NROWS / 8), dim3(256), 0, stream>>>(
      x, cwo, cbo, bngo, bnbo, bnmo, bnvo,
      cwi, cbi, bngi, bnbi, bnmi, bnvi, xbf, uo, ui);
  k_expand<<<dim3(2048), dim3(256), 0, stream>>>(uo, e16o, ebo, Lbuf);
  k_select<false><<<dim3(NROWS / 4), dim3(256), 0, stream>>>(Lbuf, nullptr, sobf);
  k_expand<<<dim3(2048), dim3(256), 0, stream>>>(ui, e16i, ebi, Lbuf);
  k_select<true><<<dim3(NROWS / 4), dim3(256), 0, stream>>>(Lbuf, xbf, xsbf);
  k_main<<<dim3(1024), dim3(512), 0, stream>>>(xbf, xsbf, wtb, sobf, bias, out);
}